// Round 10
// baseline (1499.436 us; speedup 1.0000x reference)
//
#include <hip/hip_runtime.h>
#include <cmath>

// Problem constants (from reference setup_inputs)
#define Bc 8
#define Nc 4096
#define Sc 1024
#define Kc 32
#define Mc (Bc*Sc*Kc)   // 262144 rows

typedef float v2f __attribute__((ext_vector_type(2)));
typedef float f32x4 __attribute__((ext_vector_type(4)));
typedef __bf16 bf16x8 __attribute__((ext_vector_type(8)));

__device__ __forceinline__ float gelu_f(float x){
  return 0.5f*x*(1.0f + erff(x*0.70710678f));
}

// float -> bf16 bits, round-to-nearest-even
__device__ __forceinline__ unsigned short f2bf(float f){
  unsigned u = __float_as_uint(f);
  u += 0x7FFFu + ((u >> 16) & 1u);
  return (unsigned short)(u >> 16);
}

// Packed f32 ops via inline asm: per-element IEEE RN, immune to FMA contraction.
__device__ __forceinline__ v2f pk_add(v2f a, v2f b){
  v2f d; asm("v_pk_add_f32 %0, %1, %2" : "=v"(d) : "v"(a), "v"(b)); return d;
}
__device__ __forceinline__ v2f pk_mul(v2f a, v2f b){
  v2f d; asm("v_pk_mul_f32 %0, %1, %2" : "=v"(d) : "v"(a), "v"(b)); return d;
}

// DPP max-reduction steps (VALU-speed cross-lane). row_ror:n = 0x120|n.
#define ROR_MAXF(v, n) { int _t = __builtin_amdgcn_update_dpp(__float_as_int(v), __float_as_int(v), 0x120|(n), 0xF, 0xF, false); \
                         v = fmaxf(v, __int_as_float(_t)); }
#define BC15_MAXF(v)   { int _t = __builtin_amdgcn_update_dpp(__float_as_int(v), __float_as_int(v), 0x142, 0xA, 0xF, false); \
                         v = fmaxf(v, __int_as_float(_t)); }
#define BC31_MAXF(v)   { int _t = __builtin_amdgcn_update_dpp(__float_as_int(v), __float_as_int(v), 0x143, 0xC, 0xF, false); \
                         v = fmaxf(v, __int_as_float(_t)); }

#define TK(v_, i_) { const bool _t = ((v_) > Bv) || (((v_) == Bv) && ((i_) < Bi)); \
  Bv = _t ? (v_) : Bv; Bi = _t ? (i_) : Bi; }

// ---------------- fused front: blocks 0-7 FPS, 8-519 transpose, 520 tp-MLP ----------------
// FPS branch is the round-6 structure (best measured: 703 us) - do not modify.
__global__ __launch_bounds__(256) void fused_front_kernel(
    const float* __restrict__ xyz, float* __restrict__ new_xyz,
    const float* __restrict__ points, float* __restrict__ pointsT,
    const float* __restrict__ t_embed,
    const float* __restrict__ wt0, const float* __restrict__ bt0,
    const float* __restrict__ wt1, const float* __restrict__ bt1,
    const float* __restrict__ wt2, const float* __restrict__ bt2,
    float* __restrict__ tp)
{
  __shared__ __align__(16) float smem[17424];   // 69.7 KB pool
  const int bid = blockIdx.x;
  const int tid = threadIdx.x;

  if (bid < 8){
    // ================= FPS: bitwise-exact vs numpy =================
    const int b = bid;
    const int lane = tid & 63;
    const int wv = tid >> 6;                    // 0..3
    const float* xb = xyz + b*Nc*3;
    float*    skv   = smem;                     // [2][4] wave best dist (parity)
    unsigned* ski   = (unsigned*)(smem + 8);    // [2][4] wave best idx
    int*      shist = (int*)(smem + 16);        // [1024] selected indices
    float4*   c4    = (float4*)(smem + 1040);   // [4096] coord stash

    const int base = tid << 4;                  // first owned point
    float4 f[12];
    const float4* src = (const float4*)(xb + base*3);
#pragma unroll
    for (int q=0;q<12;++q) f[q] = src[q];
#define AR(i) ((i)%4==0 ? f[(i)/4].x : (i)%4==1 ? f[(i)/4].y : (i)%4==2 ? f[(i)/4].z : f[(i)/4].w)
    v2f px2[8], py2[8], pz2[8], d2[8];
#pragma unroll
    for (int k=0;k<8;++k){
      px2[k].x = AR(6*k+0); py2[k].x = AR(6*k+1); pz2[k].x = AR(6*k+2);
      px2[k].y = AR(6*k+3); py2[k].y = AR(6*k+4); pz2[k].y = AR(6*k+5);
      c4[base+2*k  ] = make_float4(px2[k].x, py2[k].x, pz2[k].x, 0.f);
      c4[base+2*k+1] = make_float4(px2[k].y, py2[k].y, pz2[k].y, 0.f);
      d2[k].x = 1e10f; d2[k].y = 1e10f;
    }
#undef AR
    __syncthreads();
    int widx = 0;                               // deterministic start at index 0
    for (int it=0; it<Sc; ++it){
      const float4 cc = c4[widx];               // single b128 LDS broadcast
      if (tid==0) shist[it] = widx;
      v2f ncx, ncy, ncz;
      ncx.x=-cc.x; ncx.y=-cc.x; ncy.x=-cc.y; ncy.y=-cc.y; ncz.x=-cc.z; ncz.y=-cc.z;
      float bvx=-1.0f, bvy=-1.0f;
#pragma unroll
      for (int k=0;k<8;++k){
        // exact numpy order: ((dx*dx + dy*dy) + dz*dz); x+(-c) == x-c bitwise
        const v2f dx = pk_add(px2[k], ncx);
        const v2f dy = pk_add(py2[k], ncy);
        const v2f dz = pk_add(pz2[k], ncz);
        const v2f dd = pk_add(pk_add(pk_mul(dx,dx), pk_mul(dy,dy)), pk_mul(dz,dz));
        v2f dn;
        dn.x = fminf(d2[k].x, dd.x);
        dn.y = fminf(d2[k].y, dd.y);
        d2[k] = dn;
        bvx = fmaxf(bvx, dn.x);
        bvy = fmaxf(bvy, dn.y);
      }
      const float bv = fmaxf(bvx, bvy);
      // lane-local lowest matching index (parallel min tree)
      unsigned bi_local = 0xFFFFFFFFu;
#pragma unroll
      for (int k=0;k<8;++k){
        const unsigned c0 = (d2[k].x == bv) ? (unsigned)(base + 2*k    ) : 0xFFFFFFFFu;
        const unsigned c1 = (d2[k].y == bv) ? (unsigned)(base + 2*k + 1) : 0xFFFFFFFFu;
        const unsigned cm = (c0 < c1) ? c0 : c1;
        bi_local = (cm < bi_local) ? cm : bi_local;
      }
      // wave max (value only): 4x row_ror + 2 bcasts, lane63 -> SGPR
      float mv = bv;
      ROR_MAXF(mv,1); ROR_MAXF(mv,2); ROR_MAXF(mv,4); ROR_MAXF(mv,8);
      BC15_MAXF(mv); BC31_MAXF(mv);
      mv = __int_as_float(__builtin_amdgcn_readlane(__float_as_int(mv), 63));
      // lowest lane with bv == mv holds the lowest matching point index
      const unsigned long long mk = __ballot(bv == mv);
      const int src_lane = __ffsll(mk) - 1;
      const unsigned bi = (unsigned)__builtin_amdgcn_readlane((int)bi_local, src_lane);
      const int p4 = (it & 1) << 2;
      if (lane==0){ skv[p4+wv] = mv; ski[p4+wv] = bi; }
      __syncthreads();                          // single barrier per iteration
      const float4 m4 = *reinterpret_cast<const float4*>(&skv[p4]);
      const uint4  i4 = *reinterpret_cast<const uint4*>(&ski[p4]);
      float Bv = m4.x; unsigned Bi = i4.x;
      TK(m4.y, i4.y) TK(m4.z, i4.z) TK(m4.w, i4.w)
      widx = (int)Bi;
    }
    __syncthreads();
    // write all centroids once
    for (int i = tid; i < Sc; i += 256){
      const float4 cc = c4[shist[i]];
      float* o = new_xyz + ((size_t)b*Sc + i)*3;
      o[0]=cc.x; o[1]=cc.y; o[2]=cc.z;
    }
  } else if (bid < 520){
    // ================= points (B,C,N) -> pointsT (B,N,C) =================
    const int t  = bid - 8;                // 0..511
    const int tb = t >> 6;                 // batch
    const int n0 = (t & 63) << 6;
    float (*tile)[65] = (float(*)[65])smem;
    const int sub = tid >> 6;              // 0..3
    const int ln  = tid & 63;
#pragma unroll 4
    for (int cp=0; cp<16; ++cp){
      const int c = (cp<<2) + sub;
      tile[c][ln] = points[((size_t)(tb*64+c))*Nc + n0 + ln];
    }
    __syncthreads();
#pragma unroll 4
    for (int np=0; np<16; ++np){
      const int nl = (np<<2) + sub;
      pointsT[((size_t)(tb*Nc + n0 + nl))*64 + ln] = tile[ln][nl];
    }
  } else {
    // ================= tp[l][b][c] = gelu(t_embed[b]) @ wt_l.T + bt_l =================
    float* ge = smem;                      // [1024]
    for (int i = tid; i < Bc*128; i += 256) ge[i] = gelu_f(t_embed[i]);
    __syncthreads();
    for (int i = tid; i < 3*Bc*68; i += 256){
      const int l = i / (Bc*68);
      const int r = i - l*(Bc*68);
      const int b = r / 68;
      const int c = r - b*68;
      const int ci = (l==0) ? 67 : 64;
      float v = 0.0f;
      if (c < ci){
        const float* wt = (l==0)?wt0:((l==1)?wt1:wt2);
        const float* bt = (l==0)?bt0:((l==1)?bt1:bt2);
        const float* w = wt + c*128;
        const float* g = ge + b*128;
        float acc = 0.0f;
        for (int t2=0;t2<128;++t2) acc = fmaf(g[t2], w[t2], acc);
        v = acc + bt[c];
      }
      tp[i] = v;
    }
  }
}

// ---------------- fused ball query + gather: 1 wave per centroid ----------------
__global__ __launch_bounds__(256) void ballgather_kernel(const float* __restrict__ xyz,
    const float* __restrict__ new_xyz, const float* __restrict__ pointsT,
    float* __restrict__ X){
  const int g = (blockIdx.x<<2) + (threadIdx.x>>6);   // centroid id in [0, B*S)
  const int lane = threadIdx.x & 63;
  const int w = threadIdx.x >> 6;
  const int b = g >> 10;
  const float* xb = xyz + b*Nc*3;
  const float cx = new_xyz[g*3+0];
  const float cy = new_xyz[g*3+1];
  const float cz = new_xyz[g*3+2];
  __shared__ int sidx[4][32];
  int total = 0;
  for (int base=0; base<Nc; base+=64){
    const int i = base + lane;
    float dx=__fsub_rn(cx, xb[i*3+0]);
    float dy=__fsub_rn(cy, xb[i*3+1]);
    float dz=__fsub_rn(cz, xb[i*3+2]);
    float sq=__fadd_rn(__fadd_rn(__fmul_rn(dx,dx),__fmul_rn(dy,dy)),__fmul_rn(dz,dz));
    bool hit = !(sq > 0.04f);                     // sqr <= R^2, matching reference exactly
    unsigned long long m = __ballot(hit);
    if (hit){
      int pos = total + (int)__popcll(m & ((1ull<<lane)-1ull));
      if (pos < 32) sidx[w][pos] = i;
    }
    total += (int)__popcll(m);
    if (total >= 32) break;
  }
  // per-wave LDS: same-wave write->read ordering handled by lgkmcnt (no barrier)
  const int fill = (total < 32) ? total : 32;     // >=1 always (centroid itself is a hit)
  const int first = sidx[w][0];
  if (lane >= fill && lane < 32) sidx[w][lane] = first;
  // gather this wave's centroid: 32 rows x 68 cols
  for (int k=0; k<32; ++k){
    const int pidx = sidx[w][k];                  // uniform within wave
    const float* pt = pointsT + ((size_t)((b<<12)+pidx))*64;
    float* xr = X + (size_t)((g<<5)+k)*68;
    float v;
    if      (lane==0) v = __fsub_rn(xb[pidx*3+0], cx);
    else if (lane==1) v = __fsub_rn(xb[pidx*3+1], cy);
    else if (lane==2) v = __fsub_rn(xb[pidx*3+2], cz);
    else              v = pt[lane-3];
    xr[lane] = v;
    if (lane < 4){
      const int c = 64 + lane;
      xr[c] = (c<67) ? pt[c-3] : 0.0f;
    }
  }
}

// ---------------- 1x1 conv via bf16 MFMA + fused input-norm+GELU + BN partials ----------------
// Stages X-tile (f32 -> norm/gelu -> +tp -> bf16) and W (bf16, [o][k]) in LDS.
// v_mfma_f32_16x16x32_bf16 fragment mapping (m89-verified family):
//   A: row=lane&15, k=(lane>>4)*8+j ; B: col=lane&15, same k ; D: col=lane&15, row=(lane>>4)*4+reg
// In-place safe (Y may alias X): all staging loads complete before barrier; stores after MFMA.
template<int NORMIN, int CI_REAL, int K_EFF, int LDX, int CO>
__global__ __launch_bounds__(256) void mm_mfma_kernel(const float* X,
    const float* __restrict__ wc, const float* __restrict__ tp,
    const float* __restrict__ sc_in, const float* __restrict__ sh_in,
    float* Y0, float* Y1, float* __restrict__ pS, float* __restrict__ pQ)
{
  constexpr int MT = 128;                 // rows per block
  constexpr int KPAD = K_EFF + 8;         // non-pow2 row stride: avoids 16-way LDS conflicts
  constexpr int NCT = CO / 16;            // col tiles per wave (wave covers all cols)
  __shared__ __align__(16) unsigned short Albs[MT][KPAD];
  __shared__ __align__(16) unsigned short Blbs[CO][KPAD];
  __shared__ __align__(16) float tpr[128];
  __shared__ __align__(16) float scN[64], shN[64];
  __shared__ float redS[4][CO], redQ[4][CO];
  const int tid = threadIdx.x;
  const int m0 = blockIdx.x * MT;
  const int b  = blockIdx.x >> 8;         // 256 blocks per batch (32768 rows)

  if (tid < 128) tpr[tid] = (tid < 68) ? tp[b*68 + tid] : 0.0f;
  if (NORMIN){
    if (tid >= 128 && tid < 192) scN[tid-128] = sc_in[tid-128];
    if (tid >= 192)              shN[tid-192] = sh_in[tid-192];
  }
  // B staging: wc[o][c] -> bf16 Blbs[o][c], zero pad c >= CI_REAL
  for (int idx = tid; idx < CO*K_EFF; idx += 256){
    const int o = idx / K_EFF, c = idx - o*K_EFF;
    Blbs[o][c] = (c < CI_REAL) ? f2bf(wc[o*CI_REAL + c]) : (unsigned short)0;
  }
  __syncthreads();                        // tpr/scN ready for A staging

  // A staging: float4 chunks, process, convert, ds_write 8B
  constexpr int CH = LDX / 4;
  for (int idx = tid; idx < MT*CH; idx += 256){
    const int r = idx / CH;
    const int c4 = (idx - r*CH) * 4;
    float4 xv = *reinterpret_cast<const float4*>(X + (size_t)(m0 + r)*LDX + c4);
    if (NORMIN){
      const float4 sci = *reinterpret_cast<const float4*>(&scN[c4]);
      const float4 shi = *reinterpret_cast<const float4*>(&shN[c4]);
      xv.x = gelu_f(fmaf(xv.x, sci.x, shi.x));
      xv.y = gelu_f(fmaf(xv.y, sci.y, shi.y));
      xv.z = gelu_f(fmaf(xv.z, sci.z, shi.z));
      xv.w = gelu_f(fmaf(xv.w, sci.w, shi.w));
    }
    const float4 tpv = *reinterpret_cast<const float4*>(&tpr[c4]);
    ushort4 o4;
    o4.x = f2bf(xv.x + tpv.x);
    o4.y = f2bf(xv.y + tpv.y);
    o4.z = f2bf(xv.z + tpv.z);
    o4.w = f2bf(xv.w + tpv.w);
    *reinterpret_cast<ushort4*>(&Albs[r][c4]) = o4;
  }
  if (K_EFF > LDX){                       // zero-fill K tail (layer 0: cols 68..95)
    constexpr int ZC = (K_EFF - LDX) / 4;
    for (int idx = tid; idx < MT*ZC; idx += 256){
      const int r = idx / ZC;
      const int c4 = LDX + (idx - r*ZC) * 4;
      *reinterpret_cast<ushort4*>(&Albs[r][c4]) = make_ushort4(0,0,0,0);
    }
  }
  __syncthreads();

  const int lane = tid & 63, wv = tid >> 6;
  const int fr = lane & 15;               // fragment row/col index
  const int kcol = (lane >> 4) * 8;       // fragment k offset
  f32x4 acc[2][NCT];
#pragma unroll
  for (int ms=0; ms<2; ++ms)
#pragma unroll
    for (int ct=0; ct<NCT; ++ct) acc[ms][ct] = (f32x4){0.f,0.f,0.f,0.f};

#pragma unroll
  for (int kk = 0; kk < K_EFF; kk += 32){
    bf16x8 bfr[NCT];
#pragma unroll
    for (int ct=0; ct<NCT; ++ct)
      bfr[ct] = *reinterpret_cast<const bf16x8*>(&Blbs[ct*16 + fr][kk + kcol]);
#pragma unroll
    for (int ms=0; ms<2; ++ms){
      const bf16x8 afr = *reinterpret_cast<const bf16x8*>(&Albs[wv*32 + ms*16 + fr][kk + kcol]);
#pragma unroll
      for (int ct=0; ct<NCT; ++ct)
        acc[ms][ct] = __builtin_amdgcn_mfma_f32_16x16x32_bf16(afr, bfr[ct], acc[ms][ct], 0, 0, 0);
    }
  }

  // store Y (fp32): D mapping col=fr, rows=(lane>>4)*4+r
  const int rr0 = (lane >> 4) * 4;
#pragma unroll
  for (int ms=0; ms<2; ++ms){
    const size_t rowb = (size_t)(m0 + wv*32 + ms*16 + rr0);
#pragma unroll
    for (int ct=0; ct<NCT; ++ct){
      float* yb = (NCT == 8 && ct >= 4) ? Y1 : Y0;
      const int col = ((NCT == 8 && ct >= 4) ? (ct-4)*16 : ct*16) + fr;
#pragma unroll
      for (int r=0; r<4; ++r)
        yb[(rowb + r)*64 + col] = acc[ms][ct][r];
    }
  }
  // BN partials: per-channel sum/sumsq from accumulators
#pragma unroll
  for (int ct=0; ct<NCT; ++ct){
    float ss = 0.f, qq = 0.f;
#pragma unroll
    for (int ms=0; ms<2; ++ms)
#pragma unroll
      for (int r=0; r<4; ++r){ const float v = acc[ms][ct][r]; ss += v; qq += v*v; }
    ss += __shfl_down(ss, 32); qq += __shfl_down(qq, 32);
    ss += __shfl_down(ss, 16); qq += __shfl_down(qq, 16);
    if (lane < 16){ redS[wv][ct*16 + lane] = ss; redQ[wv][ct*16 + lane] = qq; }
  }
  __syncthreads();
  if (tid < CO){
    const float a  = redS[0][tid] + redS[1][tid] + redS[2][tid] + redS[3][tid];
    const float bb = redQ[0][tid] + redQ[1][tid] + redQ[2][tid] + redQ[3][tid];
    pS[(size_t)blockIdx.x*CO + tid] = a;
    pQ[(size_t)blockIdx.x*CO + tid] = bb;
  }
}

// ---------------- finalize BN stats -> scale/shift ----------------
template<int CO>
__global__ __launch_bounds__(256) void finalize_kernel(const float* __restrict__ pS,
    const float* __restrict__ pQ, const float* __restrict__ g, const float* __restrict__ be,
    float* __restrict__ scale, float* __restrict__ shift, int nblk){
  __shared__ float rS[256], rQ[256];
  constexpr int NCH = 256 / CO;
  const int o  = threadIdx.x % CO;
  const int ch = threadIdx.x / CO;
  const int per = nblk / NCH;
  const int i0 = ch * per;
  float s = 0.f, q = 0.f;
  for (int i=0; i<per; ++i){
    s += pS[(size_t)(i0+i)*CO + o];
    q += pQ[(size_t)(i0+i)*CO + o];
  }
  rS[threadIdx.x] = s; rQ[threadIdx.x] = q;
  __syncthreads();
  if (threadIdx.x < CO){
    float ss = 0.f, qq = 0.f;
#pragma unroll
    for (int c=0; c<NCH; ++c){ ss += rS[c*CO + o]; qq += rQ[c*CO + o]; }
    const float inv_n = 1.0f/(float)Mc;
    const float mu = ss*inv_n;
    const float var = qq*inv_n - mu*mu;
    const float rs = 1.0f/sqrtf(var + 1e-5f);
    const float sc = rs*g[o];
    scale[o] = sc;
    shift[o] = fmaf(-mu, sc, be[o]);
  }
}

// ---------------- layer2: normalize + GELU + max over K -> new_points (B,128,S) ----------------
__global__ __launch_bounds__(256) void pool_kernel(const float* __restrict__ Y,
    const float* __restrict__ scale, const float* __restrict__ shift,
    float* __restrict__ out, int o_base){
  __shared__ float pool[32][65];
  const int tid = threadIdx.x;
  const int b  = blockIdx.x >> 5;
  const int s0 = (blockIdx.x & 31) << 5;     // 32 centroids per block
  const int c  = tid & 63;
  const int sl0 = tid >> 6;
  const float sc = scale[c], sh = shift[c];
  for (int sp=0; sp<8; ++sp){
    const int sl = (sp<<2) + sl0;
    const int s = s0 + sl;
    const float* yp = Y + ((size_t)((b<<10)+s)<<5)*64 + c;
    float mx = -1e30f;
#pragma unroll 4
    for (int k=0;k<32;++k){
      float v = yp[(size_t)(k<<6)];
      v = gelu_f(fmaf(v, sc, sh));
      mx = fmaxf(mx, v);
    }
    pool[sl][c] = mx;
  }
  __syncthreads();
  for (int p=0;p<8;++p){
    const int c2 = (p<<3) + (tid>>5);
    const int sl = tid & 31;
    out[((size_t)((b<<7) + o_base + c2)<<10) + s0 + sl] = pool[sl][c2];
  }
}

// ---------------- launch ----------------
extern "C" void kernel_launch(void* const* d_in, const int* in_sizes, int n_in,
                              void* d_out, int out_size, void* d_ws, size_t ws_size,
                              hipStream_t stream){
  const float* xyz     = (const float*)d_in[0];
  const float* points  = (const float*)d_in[1];
  const float* t_embed = (const float*)d_in[2];
  const float* wt0=(const float*)d_in[3],  *bt0=(const float*)d_in[4],  *wc0=(const float*)d_in[5];
  const float* g0 =(const float*)d_in[7],  *be0=(const float*)d_in[8];
  const float* wt1=(const float*)d_in[9],  *bt1=(const float*)d_in[10], *wc1=(const float*)d_in[11];
  const float* g1 =(const float*)d_in[13], *be1=(const float*)d_in[14];
  const float* wt2=(const float*)d_in[15], *bt2=(const float*)d_in[16], *wc2=(const float*)d_in[17];
  const float* g2 =(const float*)d_in[19], *be2=(const float*)d_in[20];

  float* out_xyz = (float*)d_out;                    // (B,S,3)
  float* out_pts = (float*)d_out + Bc*Sc*3;          // (B,128,S)

  // workspace layout (floats); total ~148.9 MB
  float* ws       = (float*)d_ws;
  float* tp       = ws + 0;                 // 2048
  float* pointsT  = ws + 2048;              // 2,097,152
  float* pS       = ws + 2099200;           // 262,144 (2048 blocks x <=128 ch)
  float* X        = ws + 2361344;           // 17,825,792 (stride-68; Yx reuse)
  float* Ya       = ws + 20187136;          // 16,777,216
  float* pQ       = ws + 36964352;          // 262,144
  float* sc0      = ws + 37226496;          // 64
  float* sh0      = sc0 + 64;
  float* sc1      = sc0 + 128;
  float* sh1      = sc0 + 192;
  float* sc2      = sc0 + 256;              // 128
  float* sh2      = sc0 + 384;              // 128
  float* Yx       = X;                      // layer-2 first-half output (stride 64)

  // front: FPS (blocks 0-7) + transpose (8-519) + tp MLP (520), overlapped
  fused_front_kernel<<<521, 256, 0, stream>>>(xyz, out_xyz, points, pointsT,
      t_embed, wt0,bt0, wt1,bt1, wt2,bt2, tp);
  // fused ball query + gather
  ballgather_kernel<<<(Bc*Sc)/4, 256, 0, stream>>>(xyz, out_xyz, pointsT, X);

  const int NBLK = Mc/128;                  // 2048 blocks per mm

  // layer 0: ci=67 (K padded to 96), co=64, no input norm
  mm_mfma_kernel<0,67,96,68,64><<<NBLK, 256, 0, stream>>>(X, wc0, tp,
      nullptr, nullptr, Ya, nullptr, pS, pQ);
  finalize_kernel<64><<<1, 256, 0, stream>>>(pS, pQ, g0, be0, sc0, sh0, NBLK);

  // layer 1: fused input norm+gelu, in-place Ya -> Ya
  mm_mfma_kernel<1,64,64,64,64><<<NBLK, 256, 0, stream>>>(Ya, wc1, tp + 544,
      sc0, sh0, Ya, nullptr, pS, pQ);
  finalize_kernel<64><<<1, 256, 0, stream>>>(pS, pQ, g1, be1, sc1, sh1, NBLK);

  // layer 2: merged co=128; cols 0-63 -> Yx, cols 64-127 -> Ya (in-place safe)
  mm_mfma_kernel<1,64,64,64,128><<<NBLK, 256, 0, stream>>>(Ya, wc2, tp + 1088,
      sc1, sh1, Yx, Ya, pS, pQ);
  finalize_kernel<128><<<1, 256, 0, stream>>>(pS, pQ, g2, be2, sc2, sh2, NBLK);

  pool_kernel<<<Bc*Sc/32, 256, 0, stream>>>(Yx, sc2,     sh2,     out_pts, 0);
  pool_kernel<<<Bc*Sc/32, 256, 0, stream>>>(Ya, sc2+64,  sh2+64,  out_pts, 64);
}